// Round 3
// baseline (120.287 us; speedup 1.0000x reference)
//
#include <hip/hip_runtime.h>
#include <math.h>

// PrecisionFocusedLoss: mean over B of ce(logits, t) * (1 + 3*penalty)
//   weight: FN (t==1,p==0) -> 4.0 ; FP (t==0,p==1) -> 16.0 ; else 1.3
// B = 8388608, C = 2. Memory-bound: ~100.7 MB in, 4 B out. Roofline ~16 us.

#define LOSS_BATCH 8388608
#define LOSS_GRID  2048
#define LOSS_BLOCK 256
#define LOSS_THREADS (LOSS_GRID * LOSS_BLOCK)          // 524288
#define LOSS_NF4     (LOSS_BATCH / 2)                  // 4194304 float4s (2 samples each)
#define LOSS_ITERS   (LOSS_NF4 / LOSS_THREADS)         // 8

// native clang vectors — __builtin_nontemporal_load requires these,
// not the HIP_vector_type structs
typedef float fvec4 __attribute__((ext_vector_type(4)));
typedef int   ivec2 __attribute__((ext_vector_type(2)));

__device__ __forceinline__ float sample_loss(float l0, float l1, int t) {
    float m   = fmaxf(l0, l1);
    float d   = fabsf(l0 - l1);
    // fast log-sum-exp; error ~1e-6, averages out over 8.4M samples
    float lse = m + __logf(1.0f + __expf(-d));
    float ce  = lse - (t ? l1 : l0);
    int p1 = (l1 > l0) ? 1 : 0;           // argmax, first-index tie-break
    float w = 1.3f;
    if (t != p1) w = t ? 4.0f : 16.0f;    // FN -> 4, FP -> 16
    return ce * w;
}

__global__ __launch_bounds__(LOSS_BLOCK) void loss_partial_kernel(
        const fvec4* __restrict__ logits4,   // 2 samples per fvec4
        const ivec2* __restrict__ tgt2,      // 2 targets per ivec2
        float*       __restrict__ partials)  // [LOSS_GRID]
{
    const int tid = blockIdx.x * LOSS_BLOCK + threadIdx.x;

    fvec4 L[LOSS_ITERS];
    ivec2 T[LOSS_ITERS];
    // issue all loads up front — 8 independent contiguous 16B + 8B loads
    #pragma unroll
    for (int j = 0; j < LOSS_ITERS; ++j) {
        int idx = j * LOSS_THREADS + tid;
        L[j] = __builtin_nontemporal_load(&logits4[idx]);
        T[j] = __builtin_nontemporal_load(&tgt2[idx]);
    }

    float acc = 0.0f;
    #pragma unroll
    for (int j = 0; j < LOSS_ITERS; ++j) {
        acc += sample_loss(L[j].x, L[j].y, T[j].x);
        acc += sample_loss(L[j].z, L[j].w, T[j].y);
    }

    // wave-64 reduction
    #pragma unroll
    for (int off = 32; off > 0; off >>= 1)
        acc += __shfl_down(acc, off, 64);
    __shared__ float smem[LOSS_BLOCK / 64];
    int lane = threadIdx.x & 63;
    int wid  = threadIdx.x >> 6;
    if (lane == 0) smem[wid] = acc;
    __syncthreads();
    if (threadIdx.x == 0) {
        float s = 0.0f;
        #pragma unroll
        for (int i = 0; i < LOSS_BLOCK / 64; ++i) s += smem[i];
        partials[blockIdx.x] = s;
    }
}

__global__ __launch_bounds__(256) void loss_final_kernel(
        const float* __restrict__ partials, float* __restrict__ out)
{
    double acc = 0.0;
    for (int i = threadIdx.x; i < LOSS_GRID; i += blockDim.x)
        acc += (double)partials[i];
    #pragma unroll
    for (int off = 32; off > 0; off >>= 1)
        acc += __shfl_down(acc, off, 64);
    __shared__ double smem[4];
    int lane = threadIdx.x & 63;
    int wid  = threadIdx.x >> 6;
    if (lane == 0) smem[wid] = acc;
    __syncthreads();
    if (threadIdx.x == 0) {
        double s = smem[0] + smem[1] + smem[2] + smem[3];
        out[0] = (float)(s / (double)LOSS_BATCH);
    }
}

extern "C" void kernel_launch(void* const* d_in, const int* in_sizes, int n_in,
                              void* d_out, int out_size, void* d_ws, size_t ws_size,
                              hipStream_t stream) {
    const fvec4* logits4 = (const fvec4*)d_in[0];
    const ivec2* tgt2    = (const ivec2*)d_in[1];
    float* partials = (float*)d_ws;           // LOSS_GRID floats = 8 KB
    float* out      = (float*)d_out;

    loss_partial_kernel<<<LOSS_GRID, LOSS_BLOCK, 0, stream>>>(logits4, tgt2, partials);
    loss_final_kernel<<<1, 256, 0, stream>>>(partials, out);
}